// Round 7
// baseline (1005.547 us; speedup 1.0000x reference)
//
#include <hip/hip_runtime.h>

#define HDIM 64
#define STEPS 3

// ---------------- embed: x[i] = emb[tokens[i]] ----------------
__global__ __launch_bounds__(256) void k_embed(const int* __restrict__ tokens,
                                               const float* __restrict__ emb,
                                               float* __restrict__ x, int n) {
  int i = blockIdx.x * 256 + threadIdx.x;
  if (i < n * HDIM) {
    int node = i >> 6;
    int h = i & 63;
    x[i] = emb[tokens[node] * HDIM + h];
  }
}

// ---------------- one-time: whT[k][j] = w_hh[j][k]  (j in 0..191) ----------------
__global__ __launch_bounds__(256) void k_whT(const float* __restrict__ w_hh,
                                             float* __restrict__ whT) {
  int t = blockIdx.x * 256 + threadIdx.x;
  if (t < HDIM * 3 * HDIM) {
    int k = t / (3 * HDIM);
    int j = t % (3 * HDIM);
    whT[t] = w_hh[j * HDIM + k];
  }
}

// ---------------- one-time: wc[s][k][j] = sum_q W_s[k][q] * w_ih[j][q] ----------------
__global__ __launch_bounds__(256) void k_wc(const float* __restrict__ W,
                                            const float* __restrict__ w_ih,
                                            float* __restrict__ wc) {
  int s = blockIdx.x;
  __shared__ float Ws[HDIM * HDIM];
  for (int t = threadIdx.x; t < HDIM * HDIM; t += 256) Ws[t] = W[s * HDIM * HDIM + t];
  __syncthreads();
  for (int o = threadIdx.x; o < HDIM * 3 * HDIM; o += 256) {
    int k = o / (3 * HDIM);
    int j = o % (3 * HDIM);
    float acc = 0.f;
#pragma unroll
    for (int q = 0; q < HDIM; ++q) acc = fmaf(Ws[k * HDIM + q], w_ih[j * HDIM + q], acc);
    wc[s * HDIM * 3 * HDIM + o] = acc;
  }
}

// ---------------- CSR build ----------------
__global__ __launch_bounds__(256) void k_hist(const int* __restrict__ dsts,
                                              int* __restrict__ deg, int ne) {
  int e = blockIdx.x * 256 + threadIdx.x;
  if (e < ne) atomicAdd(&deg[dsts[e]], 1);
}

__global__ __launch_bounds__(1024) void k_scan(const int* __restrict__ deg,
                                               int* __restrict__ rowptr, int n) {
  __shared__ int part[1024];
  const int t = threadIdx.x;
  const int c = (n + 1023) >> 10;
  int lo = t * c;
  int hi = lo + c; if (hi > n) hi = n; if (lo > n) lo = n;
  int s = 0;
  for (int i = lo; i < hi; ++i) s += deg[i];
  part[t] = s;
  __syncthreads();
  for (int off = 1; off < 1024; off <<= 1) {
    int v = (t >= off) ? part[t - off] : 0;
    __syncthreads();
    part[t] += v;
    __syncthreads();
  }
  int run = (t == 0) ? 0 : part[t - 1];
  for (int i = lo; i < hi; ++i) {
    rowptr[i] = run;
    run += deg[i];
  }
  if (t == 1023) rowptr[n] = part[1023];
}

__global__ __launch_bounds__(256) void k_fill(const int* __restrict__ srcs,
                                              const int* __restrict__ dsts,
                                              int* __restrict__ cursor,
                                              int* __restrict__ eidx, int ne) {
  int e = blockIdx.x * 256 + threadIdx.x;
  if (e < ne) {
    int d = dsts[e];
    int p = atomicAdd(&cursor[d], 1);
    eidx[p] = srcs[e];
  }
}

// ---------------- agg rows: one wave per node; float4 lanes, 4 edge streams ----------------
__global__ __launch_bounds__(256) void k_gather4(const int* __restrict__ rowptr,
                                                 const int* __restrict__ eidx,
                                                 const float4* __restrict__ x4,
                                                 float4* __restrict__ agg4, int n) {
  const int lane = threadIdx.x & 63;
  const int wid = threadIdx.x >> 6;
  int node = blockIdx.x * 4 + wid;
  if (node >= n) return;
  const int lo = rowptr[node], hi = rowptr[node + 1];
  const int grp = lane >> 4;    // edge stream 0..3
  const int cl = lane & 15;     // float4 channel chunk
  float4 acc = make_float4(0.f, 0.f, 0.f, 0.f);
  int e = lo + grp;
  for (; e + 4 < hi; e += 8) {
    int s0 = eidx[e];
    int s1 = eidx[e + 4];
    float4 v0 = x4[(size_t)s0 * 16 + cl];
    float4 v1 = x4[(size_t)s1 * 16 + cl];
    acc.x += v0.x + v1.x;
    acc.y += v0.y + v1.y;
    acc.z += v0.z + v1.z;
    acc.w += v0.w + v1.w;
  }
  if (e < hi) {
    int s0 = eidx[e];
    float4 v0 = x4[(size_t)s0 * 16 + cl];
    acc.x += v0.x; acc.y += v0.y; acc.z += v0.z; acc.w += v0.w;
  }
#pragma unroll
  for (int off = 16; off < 64; off <<= 1) {
    acc.x += __shfl_xor(acc.x, off);
    acc.y += __shfl_xor(acc.y, off);
    acc.z += __shfl_xor(acc.z, off);
    acc.w += __shfl_xor(acc.w, off);
  }
  if (grp == 0) agg4[(size_t)node * 16 + cl] = acc;
}

// ---------------- transpose rows[n][64] -> T[64][n] ----------------
__global__ __launch_bounds__(256) void k_t_fwd(const float* __restrict__ in,
                                               float* __restrict__ out, int n) {
  __shared__ float tile[64][65];
  const int node0 = blockIdx.x * 64;
  const int wid = threadIdx.x >> 6, lane = threadIdx.x & 63;
#pragma unroll
  for (int p = 0; p < 16; ++p) {
    int r = p * 4 + wid;
    int node = node0 + r;
    tile[r][lane] = (node < n) ? in[(size_t)node * 64 + lane] : 0.f;
  }
  __syncthreads();
#pragma unroll
  for (int p = 0; p < 16; ++p) {
    int c = p * 4 + wid;
    int node = node0 + lane;
    if (node < n) out[(size_t)c * n + node] = tile[lane][c];
  }
}

// ---------------- transpose T[64][n] -> rows[n][64] ----------------
__global__ __launch_bounds__(256) void k_t_bwd(const float* __restrict__ in,
                                               float* __restrict__ out, int n) {
  __shared__ float tile[64][65];
  const int node0 = blockIdx.x * 64;
  const int wid = threadIdx.x >> 6, lane = threadIdx.x & 63;
#pragma unroll
  for (int p = 0; p < 16; ++p) {
    int c = p * 4 + wid;
    int node = node0 + lane;
    tile[c][lane] = (node < n) ? in[(size_t)c * n + node] : 0.f;
  }
  __syncthreads();
#pragma unroll
  for (int p = 0; p < 16; ++p) {
    int r = p * 4 + wid;
    int node = node0 + r;
    if (node < n) out[(size_t)node * 64 + lane] = tile[lane][r];
  }
}

// ---------------- transposed GRU: xT2 = GRU(aggT @ Wc, xT) ----------------
// lane = node. Block 512 = 8 waves = one 64-node group; wave owns 8 channels.
// Activations: coalesced loads -> LDS tile, conflict-free reads. Weights:
// wave-uniform float4 loads (L1 broadcast). 48 acc/thread, VALU-bound.
#define CT 8
__global__ __launch_bounds__(512, 2) void k_gruT(const float* __restrict__ aggT,
                                                 const float* __restrict__ xT,
                                                 float* __restrict__ xT2,
                                                 const float* __restrict__ wc,
                                                 const float* __restrict__ whT,
                                                 const float* __restrict__ b_ih,
                                                 const float* __restrict__ b_hh,
                                                 int n) {
  __shared__ float As[64 * 64];
  __shared__ float Hs[64 * 64];
  const int node0 = blockIdx.x * 64;
  const int lane = threadIdx.x & 63;
  const int wid = threadIdx.x >> 6;  // 0..7
  {
    int node = node0 + lane;
    bool ok = node < n;
    for (int r = wid; r < 64; r += 8) {
      As[r * 64 + lane] = ok ? aggT[(size_t)r * n + node] : 0.f;
      Hs[r * 64 + lane] = ok ? xT[(size_t)r * n + node] : 0.f;
    }
  }
  __syncthreads();

  const int c0 = wid * CT;
  float air[CT], aiz[CT], ain[CT], ahr[CT], ahz[CT], ahn[CT];
#pragma unroll
  for (int c = 0; c < CT; ++c) {
    air[c] = 0.f; aiz[c] = 0.f; ain[c] = 0.f;
    ahr[c] = 0.f; ahz[c] = 0.f; ahn[c] = 0.f;
  }

#pragma unroll 2
  for (int k = 0; k < 64; ++k) {
    const float a = As[k * 64 + lane];
    const float h = Hs[k * 64 + lane];
    const float* wi = wc + k * 192 + c0;
    const float* wh = whT + k * 192 + c0;
    const float4 wir0 = *(const float4*)(wi);
    const float4 wir1 = *(const float4*)(wi + 4);
    const float4 wiz0 = *(const float4*)(wi + 64);
    const float4 wiz1 = *(const float4*)(wi + 68);
    const float4 win0 = *(const float4*)(wi + 128);
    const float4 win1 = *(const float4*)(wi + 132);
    const float4 whr0 = *(const float4*)(wh);
    const float4 whr1 = *(const float4*)(wh + 4);
    const float4 whz0 = *(const float4*)(wh + 64);
    const float4 whz1 = *(const float4*)(wh + 68);
    const float4 whn0 = *(const float4*)(wh + 128);
    const float4 whn1 = *(const float4*)(wh + 132);
    air[0] = fmaf(a, wir0.x, air[0]); air[1] = fmaf(a, wir0.y, air[1]);
    air[2] = fmaf(a, wir0.z, air[2]); air[3] = fmaf(a, wir0.w, air[3]);
    air[4] = fmaf(a, wir1.x, air[4]); air[5] = fmaf(a, wir1.y, air[5]);
    air[6] = fmaf(a, wir1.z, air[6]); air[7] = fmaf(a, wir1.w, air[7]);
    aiz[0] = fmaf(a, wiz0.x, aiz[0]); aiz[1] = fmaf(a, wiz0.y, aiz[1]);
    aiz[2] = fmaf(a, wiz0.z, aiz[2]); aiz[3] = fmaf(a, wiz0.w, aiz[3]);
    aiz[4] = fmaf(a, wiz1.x, aiz[4]); aiz[5] = fmaf(a, wiz1.y, aiz[5]);
    aiz[6] = fmaf(a, wiz1.z, aiz[6]); aiz[7] = fmaf(a, wiz1.w, aiz[7]);
    ain[0] = fmaf(a, win0.x, ain[0]); ain[1] = fmaf(a, win0.y, ain[1]);
    ain[2] = fmaf(a, win0.z, ain[2]); ain[3] = fmaf(a, win0.w, ain[3]);
    ain[4] = fmaf(a, win1.x, ain[4]); ain[5] = fmaf(a, win1.y, ain[5]);
    ain[6] = fmaf(a, win1.z, ain[6]); ain[7] = fmaf(a, win1.w, ain[7]);
    ahr[0] = fmaf(h, whr0.x, ahr[0]); ahr[1] = fmaf(h, whr0.y, ahr[1]);
    ahr[2] = fmaf(h, whr0.z, ahr[2]); ahr[3] = fmaf(h, whr0.w, ahr[3]);
    ahr[4] = fmaf(h, whr1.x, ahr[4]); ahr[5] = fmaf(h, whr1.y, ahr[5]);
    ahr[6] = fmaf(h, whr1.z, ahr[6]); ahr[7] = fmaf(h, whr1.w, ahr[7]);
    ahz[0] = fmaf(h, whz0.x, ahz[0]); ahz[1] = fmaf(h, whz0.y, ahz[1]);
    ahz[2] = fmaf(h, whz0.z, ahz[2]); ahz[3] = fmaf(h, whz0.w, ahz[3]);
    ahz[4] = fmaf(h, whz1.x, ahz[4]); ahz[5] = fmaf(h, whz1.y, ahz[5]);
    ahz[6] = fmaf(h, whz1.z, ahz[6]); ahz[7] = fmaf(h, whz1.w, ahz[7]);
    ahn[0] = fmaf(h, whn0.x, ahn[0]); ahn[1] = fmaf(h, whn0.y, ahn[1]);
    ahn[2] = fmaf(h, whn0.z, ahn[2]); ahn[3] = fmaf(h, whn0.w, ahn[3]);
    ahn[4] = fmaf(h, whn1.x, ahn[4]); ahn[5] = fmaf(h, whn1.y, ahn[5]);
    ahn[6] = fmaf(h, whn1.z, ahn[6]); ahn[7] = fmaf(h, whn1.w, ahn[7]);
  }

  int node = node0 + lane;
  if (node < n) {
#pragma unroll
    for (int c = 0; c < CT; ++c) {
      int j = c0 + c;
      float r = 1.f / (1.f + __expf(-(air[c] + ahr[c] + b_ih[j] + b_hh[j])));
      float z = 1.f / (1.f + __expf(-(aiz[c] + ahz[c] + b_ih[64 + j] + b_hh[64 + j])));
      float nn = tanhf((ain[c] + b_ih[128 + j]) + r * (ahn[c] + b_hh[128 + j]));
      float h_old = Hs[j * 64 + lane];
      xT2[(size_t)j * n + node] = (1.f - z) * nn + z * h_old;
    }
  }
}

// ---------------- per-graph mean pool of relu(x); batch sorted ----------------
__device__ __forceinline__ int lower_bound_i(const int* __restrict__ a, int n, int v) {
  int lo = 0, hi = n;
  while (lo < hi) {
    int mid = (lo + hi) >> 1;
    if (a[mid] < v) lo = mid + 1; else hi = mid;
  }
  return lo;
}

__global__ __launch_bounds__(256) void k_pool(const float* __restrict__ x,
                                              const int* __restrict__ batch,
                                              float* __restrict__ pooled,
                                              int n) {
  int g = blockIdx.x;
  int lo = lower_bound_i(batch, n, g);
  int hi = lower_bound_i(batch, n, g + 1);
  const int lane = threadIdx.x & 63;
  const int w = threadIdx.x >> 6;  // 0..3
  float acc = 0.f;
  for (int i = lo + w; i < hi; i += 4) {
    acc += fmaxf(x[i * HDIM + lane], 0.f);
  }
  __shared__ float red[4][HDIM];
  red[w][lane] = acc;
  __syncthreads();
  if (w == 0) {
    float s = red[0][lane] + red[1][lane] + red[2][lane] + red[3][lane];
    float cnt = (float)(hi - lo);
    pooled[g * HDIM + lane] = s / fmaxf(cnt, 1.f);
  }
}

// ---------------- head ----------------
__global__ __launch_bounds__(256) void k_head(const float* __restrict__ pooled,
                                              const float* __restrict__ lin1_w,
                                              const float* __restrict__ lin1_b,
                                              const float* __restrict__ lout_w,
                                              const float* __restrict__ lout_b,
                                              float* __restrict__ out, int G) {
  __shared__ float P[128 * HDIM];
  __shared__ float W1T[HDIM * HDIM];
  __shared__ float H1[128 * HDIM];
  for (int t = threadIdx.x; t < G * HDIM; t += 256) P[t] = pooled[t];
  for (int t = threadIdx.x; t < HDIM * HDIM; t += 256) {
    int j = t & 63, k = t >> 6;
    W1T[k * HDIM + j] = lin1_w[j * HDIM + k];
  }
  __syncthreads();
  for (int idx = threadIdx.x; idx < G * HDIM; idx += 256) {
    int g = idx >> 6, j = idx & 63;
    float acc = lin1_b[j];
#pragma unroll
    for (int k = 0; k < HDIM; ++k) acc = fmaf(P[g * HDIM + k], W1T[k * HDIM + j], acc);
    H1[idx] = fmaxf(acc, 0.f);
  }
  __syncthreads();
  for (int idx = threadIdx.x; idx < G * 2; idx += 256) {
    int g = idx >> 1, c = idx & 1;
    float acc = lout_b[c];
#pragma unroll
    for (int j = 0; j < HDIM; ++j) acc = fmaf(H1[g * HDIM + j], lout_w[c * HDIM + j], acc);
    out[idx] = acc;
  }
}

extern "C" void kernel_launch(void* const* d_in, const int* in_sizes, int n_in,
                              void* d_out, int out_size, void* d_ws, size_t ws_size,
                              hipStream_t stream) {
  const int* tokens   = (const int*)d_in[0];
  const int* edge_idx = (const int*)d_in[1];
  const int* batch    = (const int*)d_in[2];
  const float* emb    = (const float*)d_in[3];
  const float* ggnn_w = (const float*)d_in[4];
  const float* w_ih   = (const float*)d_in[5];
  const float* w_hh   = (const float*)d_in[6];
  const float* b_ih   = (const float*)d_in[7];
  const float* b_hh   = (const float*)d_in[8];
  const float* lin1_w = (const float*)d_in[9];
  const float* lin1_b = (const float*)d_in[10];
  const float* lout_w = (const float*)d_in[11];
  const float* lout_b = (const float*)d_in[12];

  const int N = in_sizes[0];
  const int E = in_sizes[1] / 2;
  const int G = out_size / 2;

  const int* srcs = edge_idx;
  const int* dsts = edge_idx + E;

  char* ws = (char*)d_ws;
  size_t off = 0;
  auto take = [&](size_t nbytes) -> char* {
    char* p = ws + off;
    off += (nbytes + 255) & ~(size_t)255;
    return p;
  };
  size_t rowBytes = (size_t)N * HDIM * sizeof(float);
  float* x      = (float*)take(rowBytes);
  float* xTa    = (float*)take(rowBytes);
  float* xTb    = (float*)take(rowBytes);
  float* aggT   = (float*)take(rowBytes);
  float* pooled = (float*)take((size_t)G * HDIM * sizeof(float));
  float* whT_g  = (float*)take(HDIM * 3 * HDIM * sizeof(float));
  float* wc_g   = (float*)take((size_t)STEPS * HDIM * 3 * HDIM * sizeof(float));
  int* rowptr   = (int*)take((size_t)(N + 1) * sizeof(int));
  int* cursor   = (int*)take((size_t)N * sizeof(int));
  int* eidx     = (int*)take((size_t)E * sizeof(int));

  const int nb64 = (N + 63) / 64;

  // --- one-time precompute: whT, combined input weights, CSR by dst ---
  k_whT<<<(HDIM * 3 * HDIM + 255) / 256, 256, 0, stream>>>(w_hh, whT_g);
  k_wc<<<STEPS, 256, 0, stream>>>(ggnn_w, w_ih, wc_g);
  hipMemsetAsync(cursor, 0, (size_t)N * sizeof(int), stream);
  k_hist<<<(E + 255) / 256, 256, 0, stream>>>(dsts, cursor, E);
  k_scan<<<1, 1024, 0, stream>>>(cursor, rowptr, N);
  hipMemcpyAsync(cursor, rowptr, (size_t)N * sizeof(int), hipMemcpyDeviceToDevice, stream);
  k_fill<<<(E + 255) / 256, 256, 0, stream>>>(srcs, dsts, cursor, eidx, E);

  // --- embed + initial transpose ---
  k_embed<<<(N * HDIM + 255) / 256, 256, 0, stream>>>(tokens, emb, x, N);
  k_t_fwd<<<nb64, 256, 0, stream>>>(x, xTa, N);

  // --- GGNN steps (transposed state; Tout doubles as agg-row scratch) ---
  float* Tin = xTa;
  float* Tout = xTb;
  for (int s = 0; s < STEPS; ++s) {
    k_gather4<<<(N + 3) / 4, 256, 0, stream>>>(rowptr, eidx, (const float4*)x,
                                               (float4*)Tout, N);
    k_t_fwd<<<nb64, 256, 0, stream>>>(Tout, aggT, N);
    k_gruT<<<nb64, 512, 0, stream>>>(aggT, Tin, Tout,
                                     wc_g + (size_t)s * HDIM * 3 * HDIM,
                                     whT_g, b_ih, b_hh, N);
    k_t_bwd<<<nb64, 256, 0, stream>>>(Tout, x, N);
    float* tmp = Tin; Tin = Tout; Tout = tmp;
  }

  k_pool<<<G, 256, 0, stream>>>(x, batch, pooled, N);
  k_head<<<1, 256, 0, stream>>>(pooled, lin1_w, lin1_b, lout_w, lout_b,
                                (float*)d_out, G);
}

// Round 8
// 631.972 us; speedup vs baseline: 1.5911x; 1.5911x over previous
//
#include <hip/hip_runtime.h>

#define HDIM 64
#define STEPS 3

// ---------------- embed: x[i] = emb[tokens[i]] ----------------
__global__ __launch_bounds__(256) void k_embed(const int* __restrict__ tokens,
                                               const float* __restrict__ emb,
                                               float* __restrict__ x, int n) {
  int i = blockIdx.x * 256 + threadIdx.x;
  if (i < n * HDIM) {
    int node = i >> 6;
    int h = i & 63;
    x[i] = emb[tokens[node] * HDIM + h];
  }
}

// ---------------- one-time: whT[k][j] = w_hh[j][k]  (j in 0..191) ----------------
__global__ __launch_bounds__(256) void k_whT(const float* __restrict__ w_hh,
                                             float* __restrict__ whT) {
  int t = blockIdx.x * 256 + threadIdx.x;
  if (t < HDIM * 3 * HDIM) {
    int k = t / (3 * HDIM);
    int j = t % (3 * HDIM);
    whT[t] = w_hh[j * HDIM + k];
  }
}

// ---------------- one-time: wc[s][k][j] = sum_q W_s[k][q] * w_ih[j][q] ----------------
__global__ __launch_bounds__(256) void k_wc(const float* __restrict__ W,
                                            const float* __restrict__ w_ih,
                                            float* __restrict__ wc) {
  int s = blockIdx.x;
  __shared__ float Ws[HDIM * HDIM];
  for (int t = threadIdx.x; t < HDIM * HDIM; t += 256) Ws[t] = W[s * HDIM * HDIM + t];
  __syncthreads();
  for (int o = threadIdx.x; o < HDIM * 3 * HDIM; o += 256) {
    int k = o / (3 * HDIM);
    int j = o % (3 * HDIM);
    float acc = 0.f;
#pragma unroll
    for (int q = 0; q < HDIM; ++q) acc = fmaf(Ws[k * HDIM + q], w_ih[j * HDIM + q], acc);
    wc[s * HDIM * 3 * HDIM + o] = acc;
  }
}

// ---------------- CSR build ----------------
__global__ __launch_bounds__(256) void k_hist(const int* __restrict__ dsts,
                                              int* __restrict__ deg, int ne) {
  int e = blockIdx.x * 256 + threadIdx.x;
  if (e < ne) atomicAdd(&deg[dsts[e]], 1);
}

__global__ __launch_bounds__(1024) void k_scan(const int* __restrict__ deg,
                                               int* __restrict__ rowptr,
                                               int* __restrict__ cursor, int n) {
  __shared__ int part[1024];
  const int t = threadIdx.x;
  const int c = (n + 1023) >> 10;
  int lo = t * c;
  int hi = lo + c; if (hi > n) hi = n; if (lo > n) lo = n;
  int s = 0;
  for (int i = lo; i < hi; ++i) s += deg[i];
  part[t] = s;
  __syncthreads();
  for (int off = 1; off < 1024; off <<= 1) {
    int v = (t >= off) ? part[t - off] : 0;
    __syncthreads();
    part[t] += v;
    __syncthreads();
  }
  int run = (t == 0) ? 0 : part[t - 1];
  for (int i = lo; i < hi; ++i) {
    rowptr[i] = run;
    cursor[i] = run;
    run += deg[i];
  }
  if (t == 1023) rowptr[n] = part[1023];
}

__global__ __launch_bounds__(256) void k_fill(const int* __restrict__ srcs,
                                              const int* __restrict__ dsts,
                                              int* __restrict__ cursor,
                                              int* __restrict__ eidx, int ne) {
  int e = blockIdx.x * 256 + threadIdx.x;
  if (e < ne) {
    int d = dsts[e];
    int p = atomicAdd(&cursor[d], 1);
    eidx[p] = srcs[e];
  }
}

// ---------------- agg rows: one wave per node; float4 lanes, 4 edge streams ----------------
__global__ __launch_bounds__(256) void k_gather4(const int* __restrict__ rowptr,
                                                 const int* __restrict__ eidx,
                                                 const float4* __restrict__ x4,
                                                 float4* __restrict__ agg4, int n) {
  const int lane = threadIdx.x & 63;
  const int wid = threadIdx.x >> 6;
  int node = blockIdx.x * 4 + wid;
  if (node >= n) return;
  const int lo = rowptr[node], hi = rowptr[node + 1];
  const int grp = lane >> 4;    // edge stream 0..3
  const int cl = lane & 15;     // float4 channel chunk
  float4 acc = make_float4(0.f, 0.f, 0.f, 0.f);
  int e = lo + grp;
  for (; e + 4 < hi; e += 8) {
    int s0 = eidx[e];
    int s1 = eidx[e + 4];
    float4 v0 = x4[(size_t)s0 * 16 + cl];
    float4 v1 = x4[(size_t)s1 * 16 + cl];
    acc.x += v0.x + v1.x;
    acc.y += v0.y + v1.y;
    acc.z += v0.z + v1.z;
    acc.w += v0.w + v1.w;
  }
  if (e < hi) {
    int s0 = eidx[e];
    float4 v0 = x4[(size_t)s0 * 16 + cl];
    acc.x += v0.x; acc.y += v0.y; acc.z += v0.z; acc.w += v0.w;
  }
#pragma unroll
  for (int off = 16; off < 64; off <<= 1) {
    acc.x += __shfl_xor(acc.x, off);
    acc.y += __shfl_xor(acc.y, off);
    acc.z += __shfl_xor(acc.z, off);
    acc.w += __shfl_xor(acc.w, off);
  }
  if (grp == 0) agg4[(size_t)node * 16 + cl] = acc;
}

// ---------------- GRU cell: x = GRU(aggx @ Wc, x) ----------------
// Lane = output channel (R6 layout). 512 thr = 8 waves, 4 nodes/wave.
// Activation broadcasts via wave-private LDS stage + uniform ds_read_b128
// (4 k-values/read) instead of 8 ds_bpermute per k. wiT in LDS (48KB),
// whT from global (L1/L2-hot). LDS total 64KB -> 2 blocks/CU.
__global__ __launch_bounds__(512, 2) void k_gru3(const float* __restrict__ agg,
                                                 float* __restrict__ x,
                                                 const float* __restrict__ wc_g,
                                                 const float* __restrict__ whT_g,
                                                 const float* __restrict__ b_ih,
                                                 const float* __restrict__ b_hh,
                                                 int n) {
  __shared__ float wiT[HDIM * 3 * HDIM];   // 48KB, [k][gate*64+lane]
  __shared__ float abuf[8][4][HDIM];       // 8KB, wave-private stage
  __shared__ float hbuf[8][4][HDIM];       // 8KB
  for (int t = threadIdx.x; t < HDIM * 3 * HDIM; t += 512) wiT[t] = wc_g[t];
  __syncthreads();

  const int lane = threadIdx.x & 63;
  const int wid = threadIdx.x >> 6;  // 0..7
  const int NG = (n + 3) >> 2;
  int g = blockIdx.x * 8 + wid;
  if (g >= NG) return;

  const float Br = b_ih[lane] + b_hh[lane];
  const float Bz = b_ih[HDIM + lane] + b_hh[HDIM + lane];
  const float Bin = b_ih[2 * HDIM + lane];
  const float Bhn = b_hh[2 * HDIM + lane];

  const int node0 = g * 4;
  float xv[4];
#pragma unroll
  for (int i = 0; i < 4; ++i) {
    int node = node0 + i;
    bool ok = (node < n);
    float av = ok ? agg[(size_t)node * HDIM + lane] : 0.f;
    xv[i] = ok ? x[(size_t)node * HDIM + lane] : 0.f;
    abuf[wid][i][lane] = av;
    hbuf[wid][i][lane] = xv[i];
  }
  // wave-private LDS: compiler orders ds write->read with lgkmcnt, no barrier.

  float ar[4] = {0, 0, 0, 0}, az[4] = {0, 0, 0, 0}, an[4] = {0, 0, 0, 0};
  float hr[4] = {0, 0, 0, 0}, hz[4] = {0, 0, 0, 0}, hn[4] = {0, 0, 0, 0};

#pragma unroll 1
  for (int kk = 0; kk < HDIM; kk += 4) {
    float wr[4], wz[4], wn[4], vr[4], vz[4], vn[4];
#pragma unroll
    for (int q = 0; q < 4; ++q) {
      int k = kk + q;
      wr[q] = wiT[k * 192 + lane];
      wz[q] = wiT[k * 192 + 64 + lane];
      wn[q] = wiT[k * 192 + 128 + lane];
      vr[q] = whT_g[k * 192 + lane];
      vz[q] = whT_g[k * 192 + 64 + lane];
      vn[q] = whT_g[k * 192 + 128 + lane];
    }
#pragma unroll
    for (int i = 0; i < 4; ++i) {
      const float4 a4 = *(const float4*)&abuf[wid][i][kk];  // uniform, broadcast
      const float4 h4 = *(const float4*)&hbuf[wid][i][kk];
      ar[i] = fmaf(a4.x, wr[0], ar[i]); az[i] = fmaf(a4.x, wz[0], az[i]); an[i] = fmaf(a4.x, wn[0], an[i]);
      hr[i] = fmaf(h4.x, vr[0], hr[i]); hz[i] = fmaf(h4.x, vz[0], hz[i]); hn[i] = fmaf(h4.x, vn[0], hn[i]);
      ar[i] = fmaf(a4.y, wr[1], ar[i]); az[i] = fmaf(a4.y, wz[1], az[i]); an[i] = fmaf(a4.y, wn[1], an[i]);
      hr[i] = fmaf(h4.y, vr[1], hr[i]); hz[i] = fmaf(h4.y, vz[1], hz[i]); hn[i] = fmaf(h4.y, vn[1], hn[i]);
      ar[i] = fmaf(a4.z, wr[2], ar[i]); az[i] = fmaf(a4.z, wz[2], az[i]); an[i] = fmaf(a4.z, wn[2], an[i]);
      hr[i] = fmaf(h4.z, vr[2], hr[i]); hz[i] = fmaf(h4.z, vz[2], hz[i]); hn[i] = fmaf(h4.z, vn[2], hn[i]);
      ar[i] = fmaf(a4.w, wr[3], ar[i]); az[i] = fmaf(a4.w, wz[3], az[i]); an[i] = fmaf(a4.w, wn[3], an[i]);
      hr[i] = fmaf(h4.w, vr[3], hr[i]); hz[i] = fmaf(h4.w, vz[3], hz[i]); hn[i] = fmaf(h4.w, vn[3], hn[i]);
    }
  }

#pragma unroll
  for (int i = 0; i < 4; ++i) {
    int node = node0 + i;
    if (node < n) {
      float r = 1.f / (1.f + __expf(-(ar[i] + hr[i] + Br)));
      float z = 1.f / (1.f + __expf(-(az[i] + hz[i] + Bz)));
      float nn = tanhf((an[i] + Bin) + r * (hn[i] + Bhn));
      x[(size_t)node * HDIM + lane] = (1.f - z) * nn + z * xv[i];
    }
  }
}

// ---------------- per-graph mean pool of relu(x); batch sorted ----------------
__device__ __forceinline__ int lower_bound_i(const int* __restrict__ a, int n, int v) {
  int lo = 0, hi = n;
  while (lo < hi) {
    int mid = (lo + hi) >> 1;
    if (a[mid] < v) lo = mid + 1; else hi = mid;
  }
  return lo;
}

__global__ __launch_bounds__(256) void k_pool(const float* __restrict__ x,
                                              const int* __restrict__ batch,
                                              float* __restrict__ pooled,
                                              int n) {
  int g = blockIdx.x;
  int lo = lower_bound_i(batch, n, g);
  int hi = lower_bound_i(batch, n, g + 1);
  const int lane = threadIdx.x & 63;
  const int w = threadIdx.x >> 6;  // 0..3
  float acc = 0.f;
  for (int i = lo + w; i < hi; i += 4) {
    acc += fmaxf(x[i * HDIM + lane], 0.f);
  }
  __shared__ float red[4][HDIM];
  red[w][lane] = acc;
  __syncthreads();
  if (w == 0) {
    float s = red[0][lane] + red[1][lane] + red[2][lane] + red[3][lane];
    float cnt = (float)(hi - lo);
    pooled[g * HDIM + lane] = s / fmaxf(cnt, 1.f);
  }
}

// ---------------- head ----------------
__global__ __launch_bounds__(256) void k_head(const float* __restrict__ pooled,
                                              const float* __restrict__ lin1_w,
                                              const float* __restrict__ lin1_b,
                                              const float* __restrict__ lout_w,
                                              const float* __restrict__ lout_b,
                                              float* __restrict__ out, int G) {
  __shared__ float P[128 * HDIM];
  __shared__ float W1T[HDIM * HDIM];
  __shared__ float H1[128 * HDIM];
  for (int t = threadIdx.x; t < G * HDIM; t += 256) P[t] = pooled[t];
  for (int t = threadIdx.x; t < HDIM * HDIM; t += 256) {
    int j = t & 63, k = t >> 6;
    W1T[k * HDIM + j] = lin1_w[j * HDIM + k];
  }
  __syncthreads();
  for (int idx = threadIdx.x; idx < G * HDIM; idx += 256) {
    int g = idx >> 6, j = idx & 63;
    float acc = lin1_b[j];
#pragma unroll
    for (int k = 0; k < HDIM; ++k) acc = fmaf(P[g * HDIM + k], W1T[k * HDIM + j], acc);
    H1[idx] = fmaxf(acc, 0.f);
  }
  __syncthreads();
  for (int idx = threadIdx.x; idx < G * 2; idx += 256) {
    int g = idx >> 1, c = idx & 1;
    float acc = lout_b[c];
#pragma unroll
    for (int j = 0; j < HDIM; ++j) acc = fmaf(H1[g * HDIM + j], lout_w[c * HDIM + j], acc);
    out[idx] = acc;
  }
}

extern "C" void kernel_launch(void* const* d_in, const int* in_sizes, int n_in,
                              void* d_out, int out_size, void* d_ws, size_t ws_size,
                              hipStream_t stream) {
  const int* tokens   = (const int*)d_in[0];
  const int* edge_idx = (const int*)d_in[1];
  const int* batch    = (const int*)d_in[2];
  const float* emb    = (const float*)d_in[3];
  const float* ggnn_w = (const float*)d_in[4];
  const float* w_ih   = (const float*)d_in[5];
  const float* w_hh   = (const float*)d_in[6];
  const float* b_ih   = (const float*)d_in[7];
  const float* b_hh   = (const float*)d_in[8];
  const float* lin1_w = (const float*)d_in[9];
  const float* lin1_b = (const float*)d_in[10];
  const float* lout_w = (const float*)d_in[11];
  const float* lout_b = (const float*)d_in[12];

  const int N = in_sizes[0];
  const int E = in_sizes[1] / 2;
  const int G = out_size / 2;

  const int* srcs = edge_idx;
  const int* dsts = edge_idx + E;

  char* ws = (char*)d_ws;
  size_t off = 0;
  auto take = [&](size_t nbytes) -> char* {
    char* p = ws + off;
    off += (nbytes + 255) & ~(size_t)255;
    return p;
  };
  size_t rowBytes = (size_t)N * HDIM * sizeof(float);
  float* x      = (float*)take(rowBytes);
  float* agg    = (float*)take(rowBytes);
  float* pooled = (float*)take((size_t)G * HDIM * sizeof(float));
  float* whT_g  = (float*)take(HDIM * 3 * HDIM * sizeof(float));
  float* wc_g   = (float*)take((size_t)STEPS * HDIM * 3 * HDIM * sizeof(float));
  int* rowptr   = (int*)take((size_t)(N + 1) * sizeof(int));
  int* cursor   = (int*)take((size_t)N * sizeof(int));  // also used as deg
  int* eidx     = (int*)take((size_t)E * sizeof(int));

  // --- one-time precompute: whT, combined input weights, CSR by dst ---
  k_whT<<<(HDIM * 3 * HDIM + 255) / 256, 256, 0, stream>>>(w_hh, whT_g);
  k_wc<<<STEPS, 256, 0, stream>>>(ggnn_w, w_ih, wc_g);
  hipMemsetAsync(cursor, 0, (size_t)N * sizeof(int), stream);
  k_hist<<<(E + 255) / 256, 256, 0, stream>>>(dsts, cursor, E);
  k_scan<<<1, 1024, 0, stream>>>(cursor, rowptr, cursor, N);
  k_fill<<<(E + 255) / 256, 256, 0, stream>>>(srcs, dsts, cursor, eidx, E);

  // --- embed ---
  k_embed<<<(N * HDIM + 255) / 256, 256, 0, stream>>>(tokens, emb, x, N);

  // --- GGNN steps: gather raw x rows, fused (aggx@Wc) GRU ---
  const int NG = (N + 3) / 4;
  for (int s = 0; s < STEPS; ++s) {
    k_gather4<<<(N + 3) / 4, 256, 0, stream>>>(rowptr, eidx, (const float4*)x,
                                               (float4*)agg, N);
    k_gru3<<<(NG + 7) / 8, 512, 0, stream>>>(agg, x,
                                             wc_g + (size_t)s * HDIM * 3 * HDIM,
                                             whT_g, b_ih, b_hh, N);
  }

  k_pool<<<G, 256, 0, stream>>>(x, batch, pooled, N);
  k_head<<<1, 256, 0, stream>>>(pooled, lin1_w, lin1_b, lout_w, lout_b,
                                (float*)d_out, G);
}

// Round 9
// 532.052 us; speedup vs baseline: 1.8899x; 1.1878x over previous
//
#include <hip/hip_runtime.h>

#define HDIM 64
#define STEPS 3

// ---------------- embed: x[i] = emb[tokens[i]] ----------------
__global__ __launch_bounds__(256) void k_embed(const int* __restrict__ tokens,
                                               const float* __restrict__ emb,
                                               float* __restrict__ x, int n) {
  int i = blockIdx.x * 256 + threadIdx.x;
  if (i < n * HDIM) {
    int node = i >> 6;
    int h = i & 63;
    x[i] = emb[tokens[node] * HDIM + h];
  }
}

// ---------------- one-time: whT[k][j] = w_hh[j][k]  (j in 0..191) ----------------
__global__ __launch_bounds__(256) void k_whT(const float* __restrict__ w_hh,
                                             float* __restrict__ whT) {
  int t = blockIdx.x * 256 + threadIdx.x;
  if (t < HDIM * 3 * HDIM) {
    int k = t / (3 * HDIM);
    int j = t % (3 * HDIM);
    whT[t] = w_hh[j * HDIM + k];
  }
}

// ---------------- one-time: wc[s][k][j] = sum_q W_s[k][q] * w_ih[j][q] ----------------
__global__ __launch_bounds__(256) void k_wc(const float* __restrict__ W,
                                            const float* __restrict__ w_ih,
                                            float* __restrict__ wc) {
  int s = blockIdx.x;
  __shared__ float Ws[HDIM * HDIM];
  for (int t = threadIdx.x; t < HDIM * HDIM; t += 256) Ws[t] = W[s * HDIM * HDIM + t];
  __syncthreads();
  for (int o = threadIdx.x; o < HDIM * 3 * HDIM; o += 256) {
    int k = o / (3 * HDIM);
    int j = o % (3 * HDIM);
    float acc = 0.f;
#pragma unroll
    for (int q = 0; q < HDIM; ++q) acc = fmaf(Ws[k * HDIM + q], w_ih[j * HDIM + q], acc);
    wc[s * HDIM * 3 * HDIM + o] = acc;
  }
}

// ---------------- CSR build ----------------
__global__ __launch_bounds__(256) void k_hist(const int* __restrict__ dsts,
                                              int* __restrict__ deg, int ne) {
  int e = blockIdx.x * 256 + threadIdx.x;
  if (e < ne) atomicAdd(&deg[dsts[e]], 1);
}

// scan1: per-block reduce of deg chunk
__global__ __launch_bounds__(256) void k_scan1(const int* __restrict__ deg,
                                               int* __restrict__ bsum, int n) {
  __shared__ int s[256];
  const int tid = threadIdx.x;
  int i = blockIdx.x * 256 + tid;
  s[tid] = (i < n) ? deg[i] : 0;
  __syncthreads();
  for (int off = 128; off > 0; off >>= 1) {
    if (tid < off) s[tid] += s[tid + off];
    __syncthreads();
  }
  if (tid == 0) bsum[blockIdx.x] = s[0];
}

// scan2: single block, exclusive scan of block sums (supports nb up to many chunks)
__global__ __launch_bounds__(1024) void k_scan2(int* __restrict__ bsum, int nb) {
  __shared__ int s[1024];
  const int tid = threadIdx.x;
  int carry = 0;
  for (int base = 0; base < nb; base += 1024) {
    int i = base + tid;
    int v = (i < nb) ? bsum[i] : 0;
    s[tid] = v;
    __syncthreads();
    for (int off = 1; off < 1024; off <<= 1) {
      int t = (tid >= off) ? s[tid - off] : 0;
      __syncthreads();
      s[tid] += t;
      __syncthreads();
    }
    if (i < nb) bsum[i] = carry + s[tid] - v;  // exclusive
    carry += s[1023];
    __syncthreads();
  }
}

// scan3: block-local exclusive scan + block offset -> rowptr, cursor
__global__ __launch_bounds__(256) void k_scan3(const int* __restrict__ deg,
                                               const int* __restrict__ bsum,
                                               int* __restrict__ rowptr,
                                               int* __restrict__ cursor, int n) {
  __shared__ int s[256];
  const int tid = threadIdx.x;
  int i = blockIdx.x * 256 + tid;
  int v = (i < n) ? deg[i] : 0;
  s[tid] = v;
  __syncthreads();
  for (int off = 1; off < 256; off <<= 1) {
    int t = (tid >= off) ? s[tid - off] : 0;
    __syncthreads();
    s[tid] += t;
    __syncthreads();
  }
  int excl = bsum[blockIdx.x] + s[tid] - v;
  if (i < n) {
    rowptr[i] = excl;
    cursor[i] = excl;
    if (i == n - 1) rowptr[n] = excl + v;
  }
}

__global__ __launch_bounds__(256) void k_fill(const int* __restrict__ srcs,
                                              const int* __restrict__ dsts,
                                              int* __restrict__ cursor,
                                              int* __restrict__ eidx, int ne) {
  int e = blockIdx.x * 256 + threadIdx.x;
  if (e < ne) {
    int d = dsts[e];
    int p = atomicAdd(&cursor[d], 1);
    eidx[p] = srcs[e];
  }
}

// ---------------- agg rows: one wave per node; float4 lanes, 4 edge streams ----------------
__global__ __launch_bounds__(256) void k_gather4(const int* __restrict__ rowptr,
                                                 const int* __restrict__ eidx,
                                                 const float4* __restrict__ x4,
                                                 float4* __restrict__ agg4, int n) {
  const int lane = threadIdx.x & 63;
  const int wid = threadIdx.x >> 6;
  int node = blockIdx.x * 4 + wid;
  if (node >= n) return;
  const int lo = rowptr[node], hi = rowptr[node + 1];
  const int grp = lane >> 4;    // edge stream 0..3
  const int cl = lane & 15;     // float4 channel chunk
  float4 acc = make_float4(0.f, 0.f, 0.f, 0.f);
  int e = lo + grp;
  for (; e + 4 < hi; e += 8) {
    int s0 = eidx[e];
    int s1 = eidx[e + 4];
    float4 v0 = x4[(size_t)s0 * 16 + cl];
    float4 v1 = x4[(size_t)s1 * 16 + cl];
    acc.x += v0.x + v1.x;
    acc.y += v0.y + v1.y;
    acc.z += v0.z + v1.z;
    acc.w += v0.w + v1.w;
  }
  if (e < hi) {
    int s0 = eidx[e];
    float4 v0 = x4[(size_t)s0 * 16 + cl];
    acc.x += v0.x; acc.y += v0.y; acc.z += v0.z; acc.w += v0.w;
  }
#pragma unroll
  for (int off = 16; off < 64; off <<= 1) {
    acc.x += __shfl_xor(acc.x, off);
    acc.y += __shfl_xor(acc.y, off);
    acc.z += __shfl_xor(acc.z, off);
    acc.w += __shfl_xor(acc.w, off);
  }
  if (grp == 0) agg4[(size_t)node * 16 + cl] = acc;
}

// ---------------- GRU cell: x = GRU(aggx @ Wc, x) ----------------
// Lane = output channel. 512 thr = 8 waves, 4 nodes/wave. Activation
// broadcasts via wave-private LDS stage + uniform ds_read_b128. wiT in LDS,
// whT from global (L1/L2-hot). LDS 64KB -> 2 blocks/CU.
__global__ __launch_bounds__(512, 2) void k_gru3(const float* __restrict__ agg,
                                                 float* __restrict__ x,
                                                 const float* __restrict__ wc_g,
                                                 const float* __restrict__ whT_g,
                                                 const float* __restrict__ b_ih,
                                                 const float* __restrict__ b_hh,
                                                 int n) {
  __shared__ float wiT[HDIM * 3 * HDIM];   // 48KB, [k][gate*64+lane]
  __shared__ float abuf[8][4][HDIM];       // 8KB, wave-private stage
  __shared__ float hbuf[8][4][HDIM];       // 8KB
  for (int t = threadIdx.x; t < HDIM * 3 * HDIM; t += 512) wiT[t] = wc_g[t];
  __syncthreads();

  const int lane = threadIdx.x & 63;
  const int wid = threadIdx.x >> 6;  // 0..7
  const int NG = (n + 3) >> 2;
  int g = blockIdx.x * 8 + wid;
  if (g >= NG) return;

  const float Br = b_ih[lane] + b_hh[lane];
  const float Bz = b_ih[HDIM + lane] + b_hh[HDIM + lane];
  const float Bin = b_ih[2 * HDIM + lane];
  const float Bhn = b_hh[2 * HDIM + lane];

  const int node0 = g * 4;
  float xv[4];
#pragma unroll
  for (int i = 0; i < 4; ++i) {
    int node = node0 + i;
    bool ok = (node < n);
    float av = ok ? agg[(size_t)node * HDIM + lane] : 0.f;
    xv[i] = ok ? x[(size_t)node * HDIM + lane] : 0.f;
    abuf[wid][i][lane] = av;
    hbuf[wid][i][lane] = xv[i];
  }

  float ar[4] = {0, 0, 0, 0}, az[4] = {0, 0, 0, 0}, an[4] = {0, 0, 0, 0};
  float hr[4] = {0, 0, 0, 0}, hz[4] = {0, 0, 0, 0}, hn[4] = {0, 0, 0, 0};

#pragma unroll 1
  for (int kk = 0; kk < HDIM; kk += 4) {
    float wr[4], wz[4], wn[4], vr[4], vz[4], vn[4];
#pragma unroll
    for (int q = 0; q < 4; ++q) {
      int k = kk + q;
      wr[q] = wiT[k * 192 + lane];
      wz[q] = wiT[k * 192 + 64 + lane];
      wn[q] = wiT[k * 192 + 128 + lane];
      vr[q] = whT_g[k * 192 + lane];
      vz[q] = whT_g[k * 192 + 64 + lane];
      vn[q] = whT_g[k * 192 + 128 + lane];
    }
#pragma unroll
    for (int i = 0; i < 4; ++i) {
      const float4 a4 = *(const float4*)&abuf[wid][i][kk];  // uniform, broadcast
      const float4 h4 = *(const float4*)&hbuf[wid][i][kk];
      ar[i] = fmaf(a4.x, wr[0], ar[i]); az[i] = fmaf(a4.x, wz[0], az[i]); an[i] = fmaf(a4.x, wn[0], an[i]);
      hr[i] = fmaf(h4.x, vr[0], hr[i]); hz[i] = fmaf(h4.x, vz[0], hz[i]); hn[i] = fmaf(h4.x, vn[0], hn[i]);
      ar[i] = fmaf(a4.y, wr[1], ar[i]); az[i] = fmaf(a4.y, wz[1], az[i]); an[i] = fmaf(a4.y, wn[1], an[i]);
      hr[i] = fmaf(h4.y, vr[1], hr[i]); hz[i] = fmaf(h4.y, vz[1], hz[i]); hn[i] = fmaf(h4.y, vn[1], hn[i]);
      ar[i] = fmaf(a4.z, wr[2], ar[i]); az[i] = fmaf(a4.z, wz[2], az[i]); an[i] = fmaf(a4.z, wn[2], an[i]);
      hr[i] = fmaf(h4.z, vr[2], hr[i]); hz[i] = fmaf(h4.z, vz[2], hz[i]); hn[i] = fmaf(h4.z, vn[2], hn[i]);
      ar[i] = fmaf(a4.w, wr[3], ar[i]); az[i] = fmaf(a4.w, wz[3], az[i]); an[i] = fmaf(a4.w, wn[3], an[i]);
      hr[i] = fmaf(h4.w, vr[3], hr[i]); hz[i] = fmaf(h4.w, vz[3], hz[i]); hn[i] = fmaf(h4.w, vn[3], hn[i]);
    }
  }

#pragma unroll
  for (int i = 0; i < 4; ++i) {
    int node = node0 + i;
    if (node < n) {
      float r = 1.f / (1.f + __expf(-(ar[i] + hr[i] + Br)));
      float z = 1.f / (1.f + __expf(-(az[i] + hz[i] + Bz)));
      float nn = tanhf((an[i] + Bin) + r * (hn[i] + Bhn));
      x[(size_t)node * HDIM + lane] = (1.f - z) * nn + z * xv[i];
    }
  }
}

// ---------------- per-graph mean pool of relu(x); batch sorted ----------------
__device__ __forceinline__ int lower_bound_i(const int* __restrict__ a, int n, int v) {
  int lo = 0, hi = n;
  while (lo < hi) {
    int mid = (lo + hi) >> 1;
    if (a[mid] < v) lo = mid + 1; else hi = mid;
  }
  return lo;
}

__global__ __launch_bounds__(256) void k_pool(const float* __restrict__ x,
                                              const int* __restrict__ batch,
                                              float* __restrict__ pooled,
                                              int n) {
  int g = blockIdx.x;
  int lo = lower_bound_i(batch, n, g);
  int hi = lower_bound_i(batch, n, g + 1);
  const int lane = threadIdx.x & 63;
  const int w = threadIdx.x >> 6;  // 0..3
  float acc = 0.f;
  for (int i = lo + w; i < hi; i += 4) {
    acc += fmaxf(x[i * HDIM + lane], 0.f);
  }
  __shared__ float red[4][HDIM];
  red[w][lane] = acc;
  __syncthreads();
  if (w == 0) {
    float s = red[0][lane] + red[1][lane] + red[2][lane] + red[3][lane];
    float cnt = (float)(hi - lo);
    pooled[g * HDIM + lane] = s / fmaxf(cnt, 1.f);
  }
}

// ---------------- head ----------------
__global__ __launch_bounds__(256) void k_head(const float* __restrict__ pooled,
                                              const float* __restrict__ lin1_w,
                                              const float* __restrict__ lin1_b,
                                              const float* __restrict__ lout_w,
                                              const float* __restrict__ lout_b,
                                              float* __restrict__ out, int G) {
  __shared__ float P[128 * HDIM];
  __shared__ float W1T[HDIM * HDIM];
  __shared__ float H1[128 * HDIM];
  for (int t = threadIdx.x; t < G * HDIM; t += 256) P[t] = pooled[t];
  for (int t = threadIdx.x; t < HDIM * HDIM; t += 256) {
    int j = t & 63, k = t >> 6;
    W1T[k * HDIM + j] = lin1_w[j * HDIM + k];
  }
  __syncthreads();
  for (int idx = threadIdx.x; idx < G * HDIM; idx += 256) {
    int g = idx >> 6, j = idx & 63;
    float acc = lin1_b[j];
#pragma unroll
    for (int k = 0; k < HDIM; ++k) acc = fmaf(P[g * HDIM + k], W1T[k * HDIM + j], acc);
    H1[idx] = fmaxf(acc, 0.f);
  }
  __syncthreads();
  for (int idx = threadIdx.x; idx < G * 2; idx += 256) {
    int g = idx >> 1, c = idx & 1;
    float acc = lout_b[c];
#pragma unroll
    for (int j = 0; j < HDIM; ++j) acc = fmaf(H1[g * HDIM + j], lout_w[c * HDIM + j], acc);
    out[idx] = acc;
  }
}

extern "C" void kernel_launch(void* const* d_in, const int* in_sizes, int n_in,
                              void* d_out, int out_size, void* d_ws, size_t ws_size,
                              hipStream_t stream) {
  const int* tokens   = (const int*)d_in[0];
  const int* edge_idx = (const int*)d_in[1];
  const int* batch    = (const int*)d_in[2];
  const float* emb    = (const float*)d_in[3];
  const float* ggnn_w = (const float*)d_in[4];
  const float* w_ih   = (const float*)d_in[5];
  const float* w_hh   = (const float*)d_in[6];
  const float* b_ih   = (const float*)d_in[7];
  const float* b_hh   = (const float*)d_in[8];
  const float* lin1_w = (const float*)d_in[9];
  const float* lin1_b = (const float*)d_in[10];
  const float* lout_w = (const float*)d_in[11];
  const float* lout_b = (const float*)d_in[12];

  const int N = in_sizes[0];
  const int E = in_sizes[1] / 2;
  const int G = out_size / 2;

  const int* srcs = edge_idx;
  const int* dsts = edge_idx + E;

  char* ws = (char*)d_ws;
  size_t off = 0;
  auto take = [&](size_t nbytes) -> char* {
    char* p = ws + off;
    off += (nbytes + 255) & ~(size_t)255;
    return p;
  };
  size_t rowBytes = (size_t)N * HDIM * sizeof(float);
  const int nb256 = (N + 255) / 256;
  float* x      = (float*)take(rowBytes);
  float* agg    = (float*)take(rowBytes);
  float* pooled = (float*)take((size_t)G * HDIM * sizeof(float));
  float* whT_g  = (float*)take(HDIM * 3 * HDIM * sizeof(float));
  float* wc_g   = (float*)take((size_t)STEPS * HDIM * 3 * HDIM * sizeof(float));
  int* rowptr   = (int*)take((size_t)(N + 1) * sizeof(int));
  int* cursor   = (int*)take((size_t)N * sizeof(int));  // also used as deg
  int* bsum     = (int*)take((size_t)nb256 * sizeof(int));
  int* eidx     = (int*)take((size_t)E * sizeof(int));

  // --- one-time precompute: whT, combined input weights, CSR by dst ---
  k_whT<<<(HDIM * 3 * HDIM + 255) / 256, 256, 0, stream>>>(w_hh, whT_g);
  k_wc<<<STEPS, 256, 0, stream>>>(ggnn_w, w_ih, wc_g);
  hipMemsetAsync(cursor, 0, (size_t)N * sizeof(int), stream);
  k_hist<<<(E + 255) / 256, 256, 0, stream>>>(dsts, cursor, E);
  k_scan1<<<nb256, 256, 0, stream>>>(cursor, bsum, N);
  k_scan2<<<1, 1024, 0, stream>>>(bsum, nb256);
  k_scan3<<<nb256, 256, 0, stream>>>(cursor, bsum, rowptr, cursor, N);
  k_fill<<<(E + 255) / 256, 256, 0, stream>>>(srcs, dsts, cursor, eidx, E);

  // --- embed ---
  k_embed<<<(N * HDIM + 255) / 256, 256, 0, stream>>>(tokens, emb, x, N);

  // --- GGNN steps: gather raw x rows, fused (aggx@Wc) GRU ---
  const int NG = (N + 3) / 4;
  for (int s = 0; s < STEPS; ++s) {
    k_gather4<<<(N + 3) / 4, 256, 0, stream>>>(rowptr, eidx, (const float4*)x,
                                               (float4*)agg, N);
    k_gru3<<<(NG + 7) / 8, 512, 0, stream>>>(agg, x,
                                             wc_g + (size_t)s * HDIM * 3 * HDIM,
                                             whT_g, b_ih, b_hh, N);
  }

  k_pool<<<G, 256, 0, stream>>>(x, batch, pooled, N);
  k_head<<<1, 256, 0, stream>>>(pooled, lin1_w, lin1_b, lout_w, lout_b,
                                (float*)d_out, G);
}

// Round 10
// 452.148 us; speedup vs baseline: 2.2239x; 1.1767x over previous
//
#include <hip/hip_runtime.h>

#define HDIM 64
#define STEPS 3

// ---------------- embed: x[i] = emb[tokens[i]] ----------------
__global__ __launch_bounds__(256) void k_embed(const int* __restrict__ tokens,
                                               const float* __restrict__ emb,
                                               float* __restrict__ x, int n) {
  int i = blockIdx.x * 256 + threadIdx.x;
  if (i < n * HDIM) {
    int node = i >> 6;
    int h = i & 63;
    x[i] = emb[tokens[node] * HDIM + h];
  }
}

// ---------------- one-time: whT[k][j] = w_hh[j][k]  (j in 0..191) ----------------
__global__ __launch_bounds__(256) void k_whT(const float* __restrict__ w_hh,
                                             float* __restrict__ whT) {
  int t = blockIdx.x * 256 + threadIdx.x;
  if (t < HDIM * 3 * HDIM) {
    int k = t / (3 * HDIM);
    int j = t % (3 * HDIM);
    whT[t] = w_hh[j * HDIM + k];
  }
}

// ---------------- one-time: wc[s][k][j] = dot(W_s[k][:], w_ih[j][:]) ----------------
// Flattened: one thread per output element (STEPS*64*192 = 36864 threads).
__global__ __launch_bounds__(256) void k_wc2(const float* __restrict__ W,
                                             const float* __restrict__ w_ih,
                                             float* __restrict__ wc, int total) {
  int o = blockIdx.x * 256 + threadIdx.x;
  if (o >= total) return;
  int s = o / (HDIM * 3 * HDIM);
  int rem = o - s * (HDIM * 3 * HDIM);
  int k = rem / (3 * HDIM);
  int j = rem - k * (3 * HDIM);
  const float4* a4 = (const float4*)(W + (size_t)s * HDIM * HDIM + (size_t)k * HDIM);
  const float4* b4 = (const float4*)(w_ih + (size_t)j * HDIM);
  float acc = 0.f;
#pragma unroll
  for (int q = 0; q < HDIM / 4; ++q) {
    float4 a = a4[q];
    float4 b = b4[q];
    acc = fmaf(a.x, b.x, acc);
    acc = fmaf(a.y, b.y, acc);
    acc = fmaf(a.z, b.z, acc);
    acc = fmaf(a.w, b.w, acc);
  }
  wc[o] = acc;
}

// ---------------- CSR build ----------------
__global__ __launch_bounds__(256) void k_hist(const int* __restrict__ dsts,
                                              int* __restrict__ deg, int ne) {
  int e = blockIdx.x * 256 + threadIdx.x;
  if (e < ne) atomicAdd(&deg[dsts[e]], 1);
}

// scan1: per-block reduce of deg chunk
__global__ __launch_bounds__(256) void k_scan1(const int* __restrict__ deg,
                                               int* __restrict__ bsum, int n) {
  __shared__ int s[256];
  const int tid = threadIdx.x;
  int i = blockIdx.x * 256 + tid;
  s[tid] = (i < n) ? deg[i] : 0;
  __syncthreads();
  for (int off = 128; off > 0; off >>= 1) {
    if (tid < off) s[tid] += s[tid + off];
    __syncthreads();
  }
  if (tid == 0) bsum[blockIdx.x] = s[0];
}

// scan2: single block, exclusive scan of block sums
__global__ __launch_bounds__(1024) void k_scan2(int* __restrict__ bsum, int nb) {
  __shared__ int s[1024];
  const int tid = threadIdx.x;
  int carry = 0;
  for (int base = 0; base < nb; base += 1024) {
    int i = base + tid;
    int v = (i < nb) ? bsum[i] : 0;
    s[tid] = v;
    __syncthreads();
    for (int off = 1; off < 1024; off <<= 1) {
      int t = (tid >= off) ? s[tid - off] : 0;
      __syncthreads();
      s[tid] += t;
      __syncthreads();
    }
    if (i < nb) bsum[i] = carry + s[tid] - v;  // exclusive
    carry += s[1023];
    __syncthreads();
  }
}

// scan3: block-local exclusive scan + block offset -> rowptr, cursor
__global__ __launch_bounds__(256) void k_scan3(const int* __restrict__ deg,
                                               const int* __restrict__ bsum,
                                               int* __restrict__ rowptr,
                                               int* __restrict__ cursor, int n) {
  __shared__ int s[256];
  const int tid = threadIdx.x;
  int i = blockIdx.x * 256 + tid;
  int v = (i < n) ? deg[i] : 0;
  s[tid] = v;
  __syncthreads();
  for (int off = 1; off < 256; off <<= 1) {
    int t = (tid >= off) ? s[tid - off] : 0;
    __syncthreads();
    s[tid] += t;
    __syncthreads();
  }
  int excl = bsum[blockIdx.x] + s[tid] - v;
  if (i < n) {
    rowptr[i] = excl;
    cursor[i] = excl;
    if (i == n - 1) rowptr[n] = excl + v;
  }
}

__global__ __launch_bounds__(256) void k_fill(const int* __restrict__ srcs,
                                              const int* __restrict__ dsts,
                                              int* __restrict__ cursor,
                                              int* __restrict__ eidx, int ne) {
  int e = blockIdx.x * 256 + threadIdx.x;
  if (e < ne) {
    int d = dsts[e];
    int p = atomicAdd(&cursor[d], 1);
    eidx[p] = srcs[e];
  }
}

// ---------------- agg rows: one wave per node; float4 lanes, 4 edge streams ----------------
__global__ __launch_bounds__(256) void k_gather4(const int* __restrict__ rowptr,
                                                 const int* __restrict__ eidx,
                                                 const float4* __restrict__ x4,
                                                 float4* __restrict__ agg4, int n) {
  const int lane = threadIdx.x & 63;
  const int wid = threadIdx.x >> 6;
  int node = blockIdx.x * 4 + wid;
  if (node >= n) return;
  const int lo = rowptr[node], hi = rowptr[node + 1];
  const int grp = lane >> 4;    // edge stream 0..3
  const int cl = lane & 15;     // float4 channel chunk
  float4 acc = make_float4(0.f, 0.f, 0.f, 0.f);
  int e = lo + grp;
  for (; e + 4 < hi; e += 8) {
    int s0 = eidx[e];
    int s1 = eidx[e + 4];
    float4 v0 = x4[(size_t)s0 * 16 + cl];
    float4 v1 = x4[(size_t)s1 * 16 + cl];
    acc.x += v0.x + v1.x;
    acc.y += v0.y + v1.y;
    acc.z += v0.z + v1.z;
    acc.w += v0.w + v1.w;
  }
  if (e < hi) {
    int s0 = eidx[e];
    float4 v0 = x4[(size_t)s0 * 16 + cl];
    acc.x += v0.x; acc.y += v0.y; acc.z += v0.z; acc.w += v0.w;
  }
#pragma unroll
  for (int off = 16; off < 64; off <<= 1) {
    acc.x += __shfl_xor(acc.x, off);
    acc.y += __shfl_xor(acc.y, off);
    acc.z += __shfl_xor(acc.z, off);
    acc.w += __shfl_xor(acc.w, off);
  }
  if (grp == 0) agg4[(size_t)node * 16 + cl] = acc;
}

// ---------------- GRU cell: x = GRU(aggx @ Wc, x) ----------------
// Lane = output channel. 512 thr = 8 waves, 4 nodes/wave. Activation
// broadcasts via wave-private LDS stage + uniform ds_read_b128. wiT in LDS,
// whT from global (L1/L2-hot). LDS 64KB -> 2 blocks/CU.
__global__ __launch_bounds__(512, 2) void k_gru3(const float* __restrict__ agg,
                                                 float* __restrict__ x,
                                                 const float* __restrict__ wc_g,
                                                 const float* __restrict__ whT_g,
                                                 const float* __restrict__ b_ih,
                                                 const float* __restrict__ b_hh,
                                                 int n) {
  __shared__ float wiT[HDIM * 3 * HDIM];   // 48KB, [k][gate*64+lane]
  __shared__ float abuf[8][4][HDIM];       // 8KB, wave-private stage
  __shared__ float hbuf[8][4][HDIM];       // 8KB
  for (int t = threadIdx.x; t < HDIM * 3 * HDIM; t += 512) wiT[t] = wc_g[t];
  __syncthreads();

  const int lane = threadIdx.x & 63;
  const int wid = threadIdx.x >> 6;  // 0..7
  const int NG = (n + 3) >> 2;
  int g = blockIdx.x * 8 + wid;
  if (g >= NG) return;

  const float Br = b_ih[lane] + b_hh[lane];
  const float Bz = b_ih[HDIM + lane] + b_hh[HDIM + lane];
  const float Bin = b_ih[2 * HDIM + lane];
  const float Bhn = b_hh[2 * HDIM + lane];

  const int node0 = g * 4;
  float xv[4];
#pragma unroll
  for (int i = 0; i < 4; ++i) {
    int node = node0 + i;
    bool ok = (node < n);
    float av = ok ? agg[(size_t)node * HDIM + lane] : 0.f;
    xv[i] = ok ? x[(size_t)node * HDIM + lane] : 0.f;
    abuf[wid][i][lane] = av;
    hbuf[wid][i][lane] = xv[i];
  }

  float ar[4] = {0, 0, 0, 0}, az[4] = {0, 0, 0, 0}, an[4] = {0, 0, 0, 0};
  float hr[4] = {0, 0, 0, 0}, hz[4] = {0, 0, 0, 0}, hn[4] = {0, 0, 0, 0};

#pragma unroll 1
  for (int kk = 0; kk < HDIM; kk += 4) {
    float wr[4], wz[4], wn[4], vr[4], vz[4], vn[4];
#pragma unroll
    for (int q = 0; q < 4; ++q) {
      int k = kk + q;
      wr[q] = wiT[k * 192 + lane];
      wz[q] = wiT[k * 192 + 64 + lane];
      wn[q] = wiT[k * 192 + 128 + lane];
      vr[q] = whT_g[k * 192 + lane];
      vz[q] = whT_g[k * 192 + 64 + lane];
      vn[q] = whT_g[k * 192 + 128 + lane];
    }
#pragma unroll
    for (int i = 0; i < 4; ++i) {
      const float4 a4 = *(const float4*)&abuf[wid][i][kk];  // uniform, broadcast
      const float4 h4 = *(const float4*)&hbuf[wid][i][kk];
      ar[i] = fmaf(a4.x, wr[0], ar[i]); az[i] = fmaf(a4.x, wz[0], az[i]); an[i] = fmaf(a4.x, wn[0], an[i]);
      hr[i] = fmaf(h4.x, vr[0], hr[i]); hz[i] = fmaf(h4.x, vz[0], hz[i]); hn[i] = fmaf(h4.x, vn[0], hn[i]);
      ar[i] = fmaf(a4.y, wr[1], ar[i]); az[i] = fmaf(a4.y, wz[1], az[i]); an[i] = fmaf(a4.y, wn[1], an[i]);
      hr[i] = fmaf(h4.y, vr[1], hr[i]); hz[i] = fmaf(h4.y, vz[1], hz[i]); hn[i] = fmaf(h4.y, vn[1], hn[i]);
      ar[i] = fmaf(a4.z, wr[2], ar[i]); az[i] = fmaf(a4.z, wz[2], az[i]); an[i] = fmaf(a4.z, wn[2], an[i]);
      hr[i] = fmaf(h4.z, vr[2], hr[i]); hz[i] = fmaf(h4.z, vz[2], hz[i]); hn[i] = fmaf(h4.z, vn[2], hn[i]);
      ar[i] = fmaf(a4.w, wr[3], ar[i]); az[i] = fmaf(a4.w, wz[3], az[i]); an[i] = fmaf(a4.w, wn[3], an[i]);
      hr[i] = fmaf(h4.w, vr[3], hr[i]); hz[i] = fmaf(h4.w, vz[3], hz[i]); hn[i] = fmaf(h4.w, vn[3], hn[i]);
    }
  }

#pragma unroll
  for (int i = 0; i < 4; ++i) {
    int node = node0 + i;
    if (node < n) {
      float r = 1.f / (1.f + __expf(-(ar[i] + hr[i] + Br)));
      float z = 1.f / (1.f + __expf(-(az[i] + hz[i] + Bz)));
      float nn = tanhf((an[i] + Bin) + r * (hn[i] + Bhn));
      x[(size_t)node * HDIM + lane] = (1.f - z) * nn + z * xv[i];
    }
  }
}

// ---------------- per-graph mean pool of relu(x); batch sorted ----------------
__device__ __forceinline__ int lower_bound_i(const int* __restrict__ a, int n, int v) {
  int lo = 0, hi = n;
  while (lo < hi) {
    int mid = (lo + hi) >> 1;
    if (a[mid] < v) lo = mid + 1; else hi = mid;
  }
  return lo;
}

__global__ __launch_bounds__(256) void k_pool(const float* __restrict__ x,
                                              const int* __restrict__ batch,
                                              float* __restrict__ pooled,
                                              int n) {
  int g = blockIdx.x;
  int lo = lower_bound_i(batch, n, g);
  int hi = lower_bound_i(batch, n, g + 1);
  const int lane = threadIdx.x & 63;
  const int w = threadIdx.x >> 6;  // 0..3
  float acc = 0.f;
  for (int i = lo + w; i < hi; i += 4) {
    acc += fmaxf(x[i * HDIM + lane], 0.f);
  }
  __shared__ float red[4][HDIM];
  red[w][lane] = acc;
  __syncthreads();
  if (w == 0) {
    float s = red[0][lane] + red[1][lane] + red[2][lane] + red[3][lane];
    float cnt = (float)(hi - lo);
    pooled[g * HDIM + lane] = s / fmaxf(cnt, 1.f);
  }
}

// ---------------- head ----------------
__global__ __launch_bounds__(256) void k_head(const float* __restrict__ pooled,
                                              const float* __restrict__ lin1_w,
                                              const float* __restrict__ lin1_b,
                                              const float* __restrict__ lout_w,
                                              const float* __restrict__ lout_b,
                                              float* __restrict__ out, int G) {
  __shared__ float P[128 * HDIM];
  __shared__ float W1T[HDIM * HDIM];
  __shared__ float H1[128 * HDIM];
  for (int t = threadIdx.x; t < G * HDIM; t += 256) P[t] = pooled[t];
  for (int t = threadIdx.x; t < HDIM * HDIM; t += 256) {
    int j = t & 63, k = t >> 6;
    W1T[k * HDIM + j] = lin1_w[j * HDIM + k];
  }
  __syncthreads();
  for (int idx = threadIdx.x; idx < G * HDIM; idx += 256) {
    int g = idx >> 6, j = idx & 63;
    float acc = lin1_b[j];
#pragma unroll
    for (int k = 0; k < HDIM; ++k) acc = fmaf(P[g * HDIM + k], W1T[k * HDIM + j], acc);
    H1[idx] = fmaxf(acc, 0.f);
  }
  __syncthreads();
  for (int idx = threadIdx.x; idx < G * 2; idx += 256) {
    int g = idx >> 1, c = idx & 1;
    float acc = lout_b[c];
#pragma unroll
    for (int j = 0; j < HDIM; ++j) acc = fmaf(H1[g * HDIM + j], lout_w[c * HDIM + j], acc);
    out[idx] = acc;
  }
}

extern "C" void kernel_launch(void* const* d_in, const int* in_sizes, int n_in,
                              void* d_out, int out_size, void* d_ws, size_t ws_size,
                              hipStream_t stream) {
  const int* tokens   = (const int*)d_in[0];
  const int* edge_idx = (const int*)d_in[1];
  const int* batch    = (const int*)d_in[2];
  const float* emb    = (const float*)d_in[3];
  const float* ggnn_w = (const float*)d_in[4];
  const float* w_ih   = (const float*)d_in[5];
  const float* w_hh   = (const float*)d_in[6];
  const float* b_ih   = (const float*)d_in[7];
  const float* b_hh   = (const float*)d_in[8];
  const float* lin1_w = (const float*)d_in[9];
  const float* lin1_b = (const float*)d_in[10];
  const float* lout_w = (const float*)d_in[11];
  const float* lout_b = (const float*)d_in[12];

  const int N = in_sizes[0];
  const int E = in_sizes[1] / 2;
  const int G = out_size / 2;

  const int* srcs = edge_idx;
  const int* dsts = edge_idx + E;

  char* ws = (char*)d_ws;
  size_t off = 0;
  auto take = [&](size_t nbytes) -> char* {
    char* p = ws + off;
    off += (nbytes + 255) & ~(size_t)255;
    return p;
  };
  size_t rowBytes = (size_t)N * HDIM * sizeof(float);
  const int nb256 = (N + 255) / 256;
  float* x      = (float*)take(rowBytes);
  float* agg    = (float*)take(rowBytes);
  float* pooled = (float*)take((size_t)G * HDIM * sizeof(float));
  float* whT_g  = (float*)take(HDIM * 3 * HDIM * sizeof(float));
  float* wc_g   = (float*)take((size_t)STEPS * HDIM * 3 * HDIM * sizeof(float));
  int* rowptr   = (int*)take((size_t)(N + 1) * sizeof(int));
  int* cursor   = (int*)take((size_t)N * sizeof(int));  // also used as deg
  int* bsum     = (int*)take((size_t)nb256 * sizeof(int));
  int* eidx     = (int*)take((size_t)E * sizeof(int));

  // --- one-time precompute: whT, combined input weights, CSR by dst ---
  k_whT<<<(HDIM * 3 * HDIM + 255) / 256, 256, 0, stream>>>(w_hh, whT_g);
  {
    const int total = STEPS * HDIM * 3 * HDIM;
    k_wc2<<<(total + 255) / 256, 256, 0, stream>>>(ggnn_w, w_ih, wc_g, total);
  }
  hipMemsetAsync(cursor, 0, (size_t)N * sizeof(int), stream);
  k_hist<<<(E + 255) / 256, 256, 0, stream>>>(dsts, cursor, E);
  k_scan1<<<nb256, 256, 0, stream>>>(cursor, bsum, N);
  k_scan2<<<1, 1024, 0, stream>>>(bsum, nb256);
  k_scan3<<<nb256, 256, 0, stream>>>(cursor, bsum, rowptr, cursor, N);
  k_fill<<<(E + 255) / 256, 256, 0, stream>>>(srcs, dsts, cursor, eidx, E);

  // --- embed ---
  k_embed<<<(N * HDIM + 255) / 256, 256, 0, stream>>>(tokens, emb, x, N);

  // --- GGNN steps: gather raw x rows, fused (aggx@Wc) GRU ---
  const int NG = (N + 3) / 4;
  for (int s = 0; s < STEPS; ++s) {
    k_gather4<<<(N + 3) / 4, 256, 0, stream>>>(rowptr, eidx, (const float4*)x,
                                               (float4*)agg, N);
    k_gru3<<<(NG + 7) / 8, 512, 0, stream>>>(agg, x,
                                             wc_g + (size_t)s * HDIM * 3 * HDIM,
                                             whT_g, b_ih, b_hh, N);
  }

  k_pool<<<G, 256, 0, stream>>>(x, batch, pooled, N);
  k_head<<<1, 256, 0, stream>>>(pooled, lin1_w, lin1_b, lout_w, lout_b,
                                (float*)d_out, G);
}